// Round 6
// baseline (867.713 us; speedup 1.0000x reference)
//
#include <hip/hip_runtime.h>

#define NN 8192
#define EE 2048
#define BB 512
#define TT 128
#define HH 128
#define G3 384
#define MAXNNZ 256
#define MAXDEG 96

typedef __attribute__((ext_vector_type(8))) _Float16 f16x8;
typedef __attribute__((ext_vector_type(4))) float f32x4;

__device__ __forceinline__ float sigm(float x){ return 1.0f/(1.0f+__expf(-x)); }
__device__ __forceinline__ float tanhfast(float x){ return 2.0f/(1.0f+__expf(-2.0f*x)) - 1.0f; }

typedef const __attribute__((address_space(1))) unsigned int* gas_p;
typedef __attribute__((address_space(3))) unsigned int* las_p;
__device__ __forceinline__ void dma16(const float* g, float* l){
  __builtin_amdgcn_global_load_lds((gas_p)g, (las_p)l, 16, 0, 0);
}
__device__ __forceinline__ void dma4(const float* g, float* l){
  __builtin_amdgcn_global_load_lds((gas_p)g, (las_p)l, 4, 0, 0);
}

// ---- build per-edge nonzero index lists (Hbat is exactly binary) ----
__global__ __launch_bounds__(256)
void build_nnz(const float* __restrict__ Hb, int* __restrict__ idx, int* __restrict__ cnt){
  __shared__ int c;
  const int e = blockIdx.x;
  if (threadIdx.x == 0) c = 0;
  __syncthreads();
  const float* row = Hb + (size_t)e * NN;
  for (int n = threadIdx.x; n < NN; n += 256){
    if (row[n] != 0.0f){
      int p = atomicAdd(&c, 1);
      if (p < MAXNNZ) idx[e*MAXNNZ + p] = n;
    }
  }
  __syncthreads();
  if (threadIdx.x == 0) cnt[e] = (c < MAXNNZ ? c : MAXNNZ);
}

// ---- invert edge lists into per-node edge lists (removes scatter atomics) ----
__global__ __launch_bounds__(128)
void build_nodelists(const int* __restrict__ idx, const int* __restrict__ cnt,
                     int* __restrict__ ndeg, int* __restrict__ nidx){
  const int e = blockIdx.x;
  const int c = cnt[e];
  for (int k = threadIdx.x; k < c; k += 128){
    int n = idx[e*MAXNNZ + k];
    int p = atomicAdd(&ndeg[n], 1);
    if (p < MAXDEG) nidx[n*MAXDEG + p] = e;
  }
}

// ---- split (16*W) into fp16 hi/lo, row-major passthrough ----
__global__ __launch_bounds__(256)
void prep_w(const float* __restrict__ W, _Float16* __restrict__ whi,
            _Float16* __restrict__ wlo, int n){
  int i = blockIdx.x*256 + threadIdx.x;
  if (i >= n) return;
  float g = W[i] * 16.0f;
  _Float16 h = (_Float16)g;
  whi[i] = h;
  wlo[i] = (_Float16)(g - (float)h);
}

// ---- transpose + split (16*W) 128x128: wt[j,k] = 16*W[k,j] ----
__global__ __launch_bounds__(256)
void prep_wt(const float* __restrict__ W, _Float16* __restrict__ wt_hi,
             _Float16* __restrict__ wt_lo){
  int i = blockIdx.x*256 + threadIdx.x;   // 16384 total
  int k = i >> 7, j = i & 127;
  float g = W[i] * 16.0f;
  _Float16 h = (_Float16)g;
  wt_hi[j*HH + k] = h;
  wt_lo[j*HH + k] = (_Float16)(g - (float)h);
}

// ---- conv-phase MFMA GEMM: C[r,j] = rowscale[r] * (A@W + bias)  (W pre-transposed, x16)
template<bool SCALE>
__global__ __launch_bounds__(256)
void mm128_mfma(const float* __restrict__ A, const _Float16* __restrict__ Bh,
                const _Float16* __restrict__ Bl, const float* __restrict__ bias,
                const float* __restrict__ rowscale, float* __restrict__ C)
{
  const int tid = threadIdx.x;
  const int w = tid >> 6, l = tid & 63;
  const int lm = l & 15, q = l >> 4;
  const int r0 = blockIdx.x * 32;
  const int n0 = w * 32;

  f32x4 acc[2][2];
  #pragma unroll
  for (int m=0;m<2;m++)
    #pragma unroll
    for (int n=0;n<2;n++) acc[m][n] = (f32x4){0.f,0.f,0.f,0.f};

  #pragma unroll 1
  for (int ks = 0; ks < 4; ++ks){
    const int kb = ks*32 + q*8;
    f16x8 ah[2], al[2];
    #pragma unroll
    for (int m=0;m<2;m++){
      const float* pa = A + (size_t)(r0 + m*16 + lm)*HH + kb;
      float4 f0 = *(const float4*)pa;
      float4 f1 = *(const float4*)(pa+4);
      float fv[8] = {f0.x,f0.y,f0.z,f0.w,f1.x,f1.y,f1.z,f1.w};
      union { f16x8 v; _Float16 u[8]; } uh, ul;
      #pragma unroll
      for (int j=0;j<8;j++){
        _Float16 hh = (_Float16)fv[j];
        uh.u[j] = hh;
        ul.u[j] = (_Float16)(fv[j] - (float)hh);
      }
      ah[m] = uh.v; al[m] = ul.v;
    }
    #pragma unroll
    for (int n=0;n<2;n++){
      const int j = n0 + n*16 + lm;
      f16x8 bh = *(const f16x8*)(Bh + (size_t)j*HH + kb);
      f16x8 bl = *(const f16x8*)(Bl + (size_t)j*HH + kb);
      #pragma unroll
      for (int m=0;m<2;m++){
        acc[m][n] = __builtin_amdgcn_mfma_f32_16x16x32_f16(ah[m], bh, acc[m][n], 0,0,0);
        acc[m][n] = __builtin_amdgcn_mfma_f32_16x16x32_f16(al[m], bh, acc[m][n], 0,0,0);
        acc[m][n] = __builtin_amdgcn_mfma_f32_16x16x32_f16(ah[m], bl, acc[m][n], 0,0,0);
      }
    }
  }
  #pragma unroll
  for (int n=0;n<2;n++){
    const int j = n0 + n*16 + lm;
    const float bv = bias[j];
    #pragma unroll
    for (int m=0;m<2;m++){
      #pragma unroll
      for (int i=0;i<4;i++){
        int r = r0 + m*16 + q*4 + i;
        float cv = acc[m][n][i]*(1.0f/16.0f) + bv;
        if (SCALE) cv *= rowscale[r];
        C[(size_t)r*HH + j] = cv;
      }
    }
  }
}

// ---- edge gather: Eb[e,:] = invDE[e] * sum_{n in edge e} Xs[n,:] ----
__global__ __launch_bounds__(128)
void edge_gather(const float* __restrict__ Xs, const int* __restrict__ idx,
                 const int* __restrict__ cnt, const float* __restrict__ invDE,
                 float* __restrict__ Eb){
  __shared__ int sidx[MAXNNZ];
  const int e = blockIdx.x, h = threadIdx.x;
  const int c = cnt[e];
  for (int k = h; k < c; k += 128) sidx[k] = idx[e*MAXNNZ + k];
  __syncthreads();
  float acc = 0.0f;
  int k = 0;
  for (; k + 4 <= c; k += 4){
    float a0 = Xs[(size_t)sidx[k+0]*HH + h];
    float a1 = Xs[(size_t)sidx[k+1]*HH + h];
    float a2 = Xs[(size_t)sidx[k+2]*HH + h];
    float a3 = Xs[(size_t)sidx[k+3]*HH + h];
    acc += (a0 + a1) + (a2 + a3);
  }
  for (; k < c; ++k) acc += Xs[(size_t)sidx[k]*HH + h];
  Eb[e*HH + h] = invDE[e] * acc;
}

// ---- node gather: X[n,:] = epilogue( DV2[n] * sum_{e ∋ n} Eb[e,:] ) ----
template<int MODE>   // 1: relu(v)+poi   2: v
__global__ __launch_bounds__(128)
void node_gather(const float* __restrict__ Eb, const int* __restrict__ nidx,
                 const int* __restrict__ ndeg, const float* __restrict__ DV2,
                 const float* __restrict__ poi, float* __restrict__ Xo){
  __shared__ int sidx[MAXDEG];
  const int n = blockIdx.x, h = threadIdx.x;
  int c = ndeg[n]; c = c < MAXDEG ? c : MAXDEG;
  for (int k = h; k < c; k += 128) sidx[k] = nidx[n*MAXDEG + k];
  __syncthreads();
  float acc = 0.0f;
  int k = 0;
  for (; k + 4 <= c; k += 4){
    float a0 = Eb[(size_t)sidx[k+0]*HH + h];
    float a1 = Eb[(size_t)sidx[k+1]*HH + h];
    float a2 = Eb[(size_t)sidx[k+2]*HH + h];
    float a3 = Eb[(size_t)sidx[k+3]*HH + h];
    acc += (a0 + a1) + (a2 + a3);
  }
  for (; k < c; ++k) acc += Eb[(size_t)sidx[k]*HH + h];
  float v = DV2[n] * acc;
  if (MODE == 1) Xo[(size_t)n*HH + h] = fmaxf(v, 0.0f) + poi[(size_t)n*HH + h];
  else           Xo[(size_t)n*HH + h] = v;
}

__global__ __launch_bounds__(256)
void gather_emb(const float* __restrict__ X, const int* __restrict__ data, float* __restrict__ emb){
  int r = blockIdx.x*2 + (threadIdx.x >> 7);
  int h = threadIdx.x & 127;
  int n = data[r];
  emb[(size_t)r*HH + h] = X[(size_t)n*HH + h];
}

// ---- gx = (emb [+ relu(h)]) @ Wih^T + bih, MFMA fp16 hi/lo 3-product ----
template<bool FUSE>
__global__ __launch_bounds__(256)
void gx_gemm(const float* __restrict__ emb, const _Float16* __restrict__ hin,
             const _Float16* __restrict__ Whi, const _Float16* __restrict__ Wlo,
             const float* __restrict__ bih, const int* __restrict__ lens,
             float* __restrict__ gx)
{
  const int blk = blockIdx.x;
  const int b = blk >> 2, tt = blk & 3;
  const int lenb = lens[b];
  if (tt*32 >= lenb) return;
  const int tid = threadIdx.x;
  const int w = tid >> 6, l = tid & 63;
  const int lm = l & 15, q = l >> 4;
  const int r0 = b*TT + tt*32;
  const int n0 = w*96;

  f32x4 acc[2][6];
  #pragma unroll
  for (int m=0;m<2;m++)
    #pragma unroll
    for (int n=0;n<6;n++) acc[m][n] = (f32x4){0.f,0.f,0.f,0.f};

  #pragma unroll 1
  for (int ks = 0; ks < 4; ++ks){
    const int kb = ks*32 + q*8;
    f16x8 ah[2], al[2];
    #pragma unroll
    for (int m=0;m<2;m++){
      const size_t ro = (size_t)(r0 + m*16 + lm)*HH + kb;
      float4 f0 = *(const float4*)(emb + ro);
      float4 f1 = *(const float4*)(emb + ro + 4);
      float fv[8] = {f0.x,f0.y,f0.z,f0.w,f1.x,f1.y,f1.z,f1.w};
      if (FUSE){
        f16x8 hv = *(const f16x8*)(hin + ro);
        #pragma unroll
        for (int j=0;j<8;j++) fv[j] += fmaxf((float)hv[j], 0.0f);
      }
      union { f16x8 v; _Float16 u[8]; } uh, ul;
      #pragma unroll
      for (int j=0;j<8;j++){
        _Float16 hh = (_Float16)fv[j];
        uh.u[j] = hh;
        ul.u[j] = (_Float16)(fv[j] - (float)hh);
      }
      ah[m] = uh.v; al[m] = ul.v;
    }
    #pragma unroll
    for (int n=0;n<6;n++){
      const int g = n0 + n*16 + lm;
      f16x8 bh = *(const f16x8*)(Whi + (size_t)g*HH + kb);
      f16x8 bl = *(const f16x8*)(Wlo + (size_t)g*HH + kb);
      #pragma unroll
      for (int m=0;m<2;m++){
        acc[m][n] = __builtin_amdgcn_mfma_f32_16x16x32_f16(ah[m], bh, acc[m][n], 0,0,0);
        acc[m][n] = __builtin_amdgcn_mfma_f32_16x16x32_f16(al[m], bh, acc[m][n], 0,0,0);
        acc[m][n] = __builtin_amdgcn_mfma_f32_16x16x32_f16(ah[m], bl, acc[m][n], 0,0,0);
      }
    }
  }
  #pragma unroll
  for (int n=0;n<6;n++){
    const int g = n0 + n*16 + lm;
    const float bv = bih[g];
    #pragma unroll
    for (int m=0;m<2;m++){
      #pragma unroll
      for (int i=0;i<4;i++){
        int t = tt*32 + m*16 + q*4 + i;
        if (t < lenb)
          gx[((size_t)b*TT + t)*G3 + g] = acc[m][n][i]*(1.0f/16.0f) + bv;
      }
    }
  }
}

// ---- MFMA GRU scan, plain fp16 h and Whh (x16 scale). 16 batches/block, 8 waves.
// gx staged into LDS via global_load_lds, 2 steps ahead, triple-buffered.
// Counted vmcnt (never 0) + lgkm-only wait before raw s_barrier.
template<bool FINAL>
__global__ __launch_bounds__(512, 1)
void gru_scan_mfma(const float* __restrict__ gxp, const float* __restrict__ Whh,
                   const float* __restrict__ bhh, const int* __restrict__ lens,
                   _Float16* __restrict__ hout, float* __restrict__ final_out)
{
  __shared__ _Float16 hbuf[2][16*HH];        // 8 KB
  __shared__ float stage[3][16][G3];         // 72 KB
  const int tid = threadIdx.x;
  const int w = tid >> 6, lane = tid & 63;
  const int lm = lane & 15, q = lane >> 4;
  const int b0 = blockIdx.x * 16;
  const int d = w*16 + lm;

  // preload 16*Whh fragments (B operand): wf[ty][ks], plain fp16
  f16x8 wf[3][4];
  #pragma unroll
  for (int ty=0; ty<3; ++ty){
    const float* wr = Whh + (size_t)(ty*HH + d)*HH;
    #pragma unroll
    for (int ks=0; ks<4; ++ks){
      const int kb = ks*32 + q*8;
      float4 f0 = *(const float4*)(wr + kb);
      float4 f1 = *(const float4*)(wr + kb + 4);
      float fv[8] = {f0.x,f0.y,f0.z,f0.w,f1.x,f1.y,f1.z,f1.w};
      union { f16x8 v; _Float16 u[8]; } uu;
      #pragma unroll
      for (int j=0;j<8;j++) uu.u[j] = (_Float16)(fv[j] * 16.0f);
      wf[ty][ks] = uu.v;
    }
  }
  const float bR = bhh[d], bZ = bhh[HH + d], bN = bhh[2*HH + d];
  const float S = 1.0f/16.0f;

  int lenb[4];
  size_t hrow[4];
  #pragma unroll
  for (int i=0;i<4;i++){
    int bb = b0 + q*4 + i;
    lenb[i] = lens[bb];
    hrow[i] = (size_t)bb*TT*HH + d;
  }
  const int lenmax = lens[b0];   // sorted descending -> max within block

  // DMA one time-step's gx rows (16 x 384 f32) into stage[slot]; 6 calls/wave.
  auto STAGE = [&](int tt, int slot){
    #pragma unroll
    for (int rr=0; rr<2; ++rr){
      int bat = w*2 + rr;
      const float* src = gxp + ((size_t)(b0+bat)*TT + tt)*G3;
      float* dstb = &stage[slot][bat][0];
      dma16(src + lane*4, dstb);
      dma4 (src + 256 + lane, dstb + 256);
      dma4 (src + 320 + lane, dstb + 320);
    }
  };

  {   // zero h buffer 0
    unsigned int* z = (unsigned int*)&hbuf[0][0];
    for (int i = tid; i < 16*HH/2; i += 512) z[i] = 0u;
  }
  float hp[4] = {0.f,0.f,0.f,0.f};
  float fout[4] = {0.f,0.f,0.f,0.f};

  // prologue: stage t=0,1
  STAGE(0, 0);
  STAGE(1, 1);
  __builtin_amdgcn_sched_barrier(0);
  asm volatile("s_waitcnt vmcnt(6)");     // t=0 staged (t=1 still in flight)
  asm volatile("s_waitcnt lgkmcnt(0)");
  __builtin_amdgcn_s_barrier();
  __builtin_amdgcn_sched_barrier(0);

  int cur = 0, slot = 0;
  #pragma unroll 1
  for (int t = 0; t < lenmax; ++t){
    // A-frag reads (h of step t) from hbuf[cur]
    f16x8 av[4];
    #pragma unroll
    for (int ks=0; ks<4; ++ks){
      int off = (lm*256 + ks*64 + q*16) ^ ((lm & 7) << 4);
      av[ks] = *(const f16x8*)((const char*)&hbuf[cur][0] + off);
    }
    // gx for this step from LDS stage
    float xv[12];
    #pragma unroll
    for (int ty=0; ty<3; ++ty)
      #pragma unroll
      for (int i=0;i<4;i++)
        xv[ty*4+i] = stage[slot][q*4+i][ty*128 + d];

    // stage t+2 (slot (slot+2)%3 == the buffer read at step t-1, safe after barrier)
    int tt2 = t + 2; if (tt2 > TT-1) tt2 = TT-1;
    int slot2 = slot + 2; if (slot2 >= 3) slot2 -= 3;
    STAGE(tt2, slot2);

    // gh = h @ (16*Whh)^T : 3 chains x 4 deep
    f32x4 aR = (f32x4){0.f,0.f,0.f,0.f};
    f32x4 aZ = aR, aN = aR;
    #pragma unroll
    for (int ks=0; ks<4; ++ks){
      aR = __builtin_amdgcn_mfma_f32_16x16x32_f16(av[ks], wf[0][ks], aR, 0,0,0);
      aZ = __builtin_amdgcn_mfma_f32_16x16x32_f16(av[ks], wf[1][ks], aZ, 0,0,0);
      aN = __builtin_amdgcn_mfma_f32_16x16x32_f16(av[ks], wf[2][ks], aN, 0,0,0);
    }

    const int nxt = cur ^ 1;
    #pragma unroll
    for (int i=0;i<4;i++){
      float r = sigm(xv[0+i] + aR[i]*S + bR);
      float z = sigm(xv[4+i] + aZ[i]*S + bZ);
      float n = tanhfast(xv[8+i] + r*(aN[i]*S + bN));
      float hnew = (1.0f - z)*n + z*hp[i];
      hp[i] = hnew;
      int bl_ = q*4 + i;
      int off = (bl_*256 + d*2) ^ ((bl_ & 7) << 4);
      *(_Float16*)((char*)&hbuf[nxt][0] + off) = (_Float16)hnew;
      if (!FINAL){
        // unconditional: rows beyond lenb are garbage but masked downstream
        hout[hrow[i] + (size_t)t*HH] = (_Float16)hnew;
      } else {
        if (t == lenb[i] - 1) fout[i] = tanhfast(hnew);
      }
    }

    __builtin_amdgcn_sched_barrier(0);
    if constexpr (FINAL) asm volatile("s_waitcnt vmcnt(6)");
    else                 asm volatile("s_waitcnt vmcnt(10)");
    asm volatile("s_waitcnt lgkmcnt(0)");
    __builtin_amdgcn_s_barrier();
    __builtin_amdgcn_sched_barrier(0);

    cur = nxt;
    slot = (slot + 1 == 3) ? 0 : slot + 1;
  }

  if (FINAL){
    #pragma unroll
    for (int i=0;i<4;i++)
      final_out[(size_t)(b0 + q*4 + i)*HH + d] = fout[i];
  }
}

extern "C" void kernel_launch(void* const* d_in, const int* in_sizes, int n_in,
                              void* d_out, int out_size, void* d_ws, size_t ws_size,
                              hipStream_t stream)
{
  const float* Hb    = (const float*)d_in[0];
  const float* DV2   = (const float*)d_in[1];
  const float* invDE = (const float*)d_in[2];
  const int*   data  = (const int*)d_in[3];
  const int*   dlen  = (const int*)d_in[4];
  const float* poi   = (const float*)d_in[5];
  const float* w1    = (const float*)d_in[6];
  const float* b1    = (const float*)d_in[7];
  const float* w2    = (const float*)d_in[8];
  const float* b2    = (const float*)d_in[9];
  const float* Wih   = (const float*)d_in[10];
  const float* Whh   = (const float*)d_in[11];
  const float* bih   = (const float*)d_in[12];
  const float* bhh   = (const float*)d_in[13];
  float* out = (float*)d_out;

  float* ws   = (float*)d_ws;
  float* x1s  = ws;                          // N*H
  float* x2   = x1s + (size_t)NN*HH;         // N*H
  float* x3s  = x2  + (size_t)NN*HH;         // N*H
  float* x4   = x3s + (size_t)NN*HH;         // N*H
  float* ebuf = x4  + (size_t)NN*HH;         // E*H
  int*   idx  = (int*)(ebuf + (size_t)EE*HH);// E*MAXNNZ
  int*   cnt  = idx + (size_t)EE*MAXNNZ;     // E
  float* gx   = (float*)(cnt + EE);          // B*T*3H
  float* emb  = gx  + (size_t)BB*TT*G3;      // B*T*H
  _Float16* hout = (_Float16*)(emb + (size_t)BB*TT*HH); // B*T*H fp16
  _Float16* Whi  = hout + (size_t)BB*TT*HH;  // 3*384*128
  _Float16* Wlo  = Whi + (size_t)3*G3*HH;
  _Float16* w1th = Wlo + (size_t)3*G3*HH;    // 128*128 each
  _Float16* w1tl = w1th + (size_t)HH*HH;
  _Float16* w2th = w1tl + (size_t)HH*HH;
  _Float16* w2tl = w2th + (size_t)HH*HH;
  int* ndeg = (int*)(w2tl + (size_t)HH*HH);  // N
  int* nidx = ndeg + NN;                     // N*MAXDEG

  // ---- prep ----
  hipMemsetAsync(ndeg, 0, NN*sizeof(int), stream);
  build_nnz<<<EE, 256, 0, stream>>>(Hb, idx, cnt);
  build_nodelists<<<EE, 128, 0, stream>>>(idx, cnt, ndeg, nidx);
  prep_w<<<(3*G3*HH + 255)/256, 256, 0, stream>>>(Wih, Whi, Wlo, 3*G3*HH);
  prep_wt<<<HH*HH/256, 256, 0, stream>>>(w1, w1th, w1tl);
  prep_wt<<<HH*HH/256, 256, 0, stream>>>(w2, w2th, w2tl);

  // ---- hypergraph conv phase ----
  mm128_mfma<true><<<NN/32, 256, 0, stream>>>(poi, w1th, w1tl, b1, DV2, x1s);
  edge_gather<<<EE, 128, 0, stream>>>(x1s, idx, cnt, invDE, ebuf);
  node_gather<1><<<NN, 128, 0, stream>>>(ebuf, nidx, ndeg, DV2, poi, x2);
  mm128_mfma<true><<<NN/32, 256, 0, stream>>>(x2, w2th, w2tl, b2, DV2, x3s);
  edge_gather<<<EE, 128, 0, stream>>>(x3s, idx, cnt, invDE, ebuf);
  node_gather<2><<<NN, 128, 0, stream>>>(ebuf, nidx, ndeg, DV2, (const float*)nullptr, x4);
  gather_emb<<<BB*TT/2, 256, 0, stream>>>(x4, data, emb);

  // ---- GRU stack (MFMA) ----
  for (int l = 0; l < 3; ++l){
    if (l == 0)
      gx_gemm<false><<<BB*4, 256, 0, stream>>>(emb, (const _Float16*)nullptr,
          Whi + (size_t)l*G3*HH, Wlo + (size_t)l*G3*HH, bih + (size_t)l*G3, dlen, gx);
    else
      gx_gemm<true><<<BB*4, 256, 0, stream>>>(emb, hout,
          Whi + (size_t)l*G3*HH, Wlo + (size_t)l*G3*HH, bih + (size_t)l*G3, dlen, gx);
    if (l < 2)
      gru_scan_mfma<false><<<BB/16, 512, 0, stream>>>(gx, Whh + (size_t)l*G3*HH,
          bhh + (size_t)l*G3, dlen, hout, (float*)nullptr);
    else
      gru_scan_mfma<true><<<BB/16, 512, 0, stream>>>(gx, Whh + (size_t)l*G3*HH,
          bhh + (size_t)l*G3, dlen, (_Float16*)nullptr, out);
  }
}

// Round 7
// 581.455 us; speedup vs baseline: 1.4923x; 1.4923x over previous
//
#include <hip/hip_runtime.h>

#define NN 8192
#define EE 2048
#define BB 512
#define TT 128
#define HH 128
#define G3 384
#define MAXNNZ 256
#define MAXDEG 96

typedef __attribute__((ext_vector_type(8))) _Float16 f16x8;
typedef __attribute__((ext_vector_type(4))) float f32x4;

__device__ __forceinline__ float sigm(float x){ return 1.0f/(1.0f+__expf(-x)); }
__device__ __forceinline__ float tanhfast(float x){ return 2.0f/(1.0f+__expf(-2.0f*x)) - 1.0f; }

// barrier ordering LDS only; global loads/stores stay in flight.
__device__ __forceinline__ void bar_lds(){
  __builtin_amdgcn_sched_barrier(0);
  asm volatile("s_waitcnt lgkmcnt(0)\n\ts_barrier" ::: "memory");
  __builtin_amdgcn_sched_barrier(0);
}

// ---- build per-edge nonzero index lists (Hbat is exactly binary) ----
__global__ __launch_bounds__(256)
void build_nnz(const float* __restrict__ Hb, int* __restrict__ idx, int* __restrict__ cnt){
  __shared__ int c;
  const int e = blockIdx.x;
  if (threadIdx.x == 0) c = 0;
  __syncthreads();
  const float* row = Hb + (size_t)e * NN;
  for (int n = threadIdx.x; n < NN; n += 256){
    if (row[n] != 0.0f){
      int p = atomicAdd(&c, 1);
      if (p < MAXNNZ) idx[e*MAXNNZ + p] = n;
    }
  }
  __syncthreads();
  if (threadIdx.x == 0) cnt[e] = (c < MAXNNZ ? c : MAXNNZ);
}

// ---- invert edge lists into per-node edge lists (removes scatter atomics) ----
__global__ __launch_bounds__(128)
void build_nodelists(const int* __restrict__ idx, const int* __restrict__ cnt,
                     int* __restrict__ ndeg, int* __restrict__ nidx){
  const int e = blockIdx.x;
  const int c = cnt[e];
  for (int k = threadIdx.x; k < c; k += 128){
    int n = idx[e*MAXNNZ + k];
    int p = atomicAdd(&ndeg[n], 1);
    if (p < MAXDEG) nidx[n*MAXDEG + p] = e;
  }
}

// ---- split (16*W) into fp16 hi/lo, row-major passthrough ----
__global__ __launch_bounds__(256)
void prep_w(const float* __restrict__ W, _Float16* __restrict__ whi,
            _Float16* __restrict__ wlo, int n){
  int i = blockIdx.x*256 + threadIdx.x;
  if (i >= n) return;
  float g = W[i] * 16.0f;
  _Float16 h = (_Float16)g;
  whi[i] = h;
  wlo[i] = (_Float16)(g - (float)h);
}

// ---- transpose + split (16*W) 128x128: wt[j,k] = 16*W[k,j] ----
__global__ __launch_bounds__(256)
void prep_wt(const float* __restrict__ W, _Float16* __restrict__ wt_hi,
             _Float16* __restrict__ wt_lo){
  int i = blockIdx.x*256 + threadIdx.x;   // 16384 total
  int k = i >> 7, j = i & 127;
  float g = W[i] * 16.0f;
  _Float16 h = (_Float16)g;
  wt_hi[j*HH + k] = h;
  wt_lo[j*HH + k] = (_Float16)(g - (float)h);
}

// ---- conv-phase MFMA GEMM: C[r,j] = rowscale[r] * (A@W + bias)  (W pre-transposed, x16)
template<bool SCALE>
__global__ __launch_bounds__(256)
void mm128_mfma(const float* __restrict__ A, const _Float16* __restrict__ Bh,
                const _Float16* __restrict__ Bl, const float* __restrict__ bias,
                const float* __restrict__ rowscale, float* __restrict__ C)
{
  const int tid = threadIdx.x;
  const int w = tid >> 6, l = tid & 63;
  const int lm = l & 15, q = l >> 4;
  const int r0 = blockIdx.x * 32;
  const int n0 = w * 32;

  f32x4 acc[2][2];
  #pragma unroll
  for (int m=0;m<2;m++)
    #pragma unroll
    for (int n=0;n<2;n++) acc[m][n] = (f32x4){0.f,0.f,0.f,0.f};

  #pragma unroll 1
  for (int ks = 0; ks < 4; ++ks){
    const int kb = ks*32 + q*8;
    f16x8 ah[2], al[2];
    #pragma unroll
    for (int m=0;m<2;m++){
      const float* pa = A + (size_t)(r0 + m*16 + lm)*HH + kb;
      float4 f0 = *(const float4*)pa;
      float4 f1 = *(const float4*)(pa+4);
      float fv[8] = {f0.x,f0.y,f0.z,f0.w,f1.x,f1.y,f1.z,f1.w};
      union { f16x8 v; _Float16 u[8]; } uh, ul;
      #pragma unroll
      for (int j=0;j<8;j++){
        _Float16 hh = (_Float16)fv[j];
        uh.u[j] = hh;
        ul.u[j] = (_Float16)(fv[j] - (float)hh);
      }
      ah[m] = uh.v; al[m] = ul.v;
    }
    #pragma unroll
    for (int n=0;n<2;n++){
      const int j = n0 + n*16 + lm;
      f16x8 bh = *(const f16x8*)(Bh + (size_t)j*HH + kb);
      f16x8 bl = *(const f16x8*)(Bl + (size_t)j*HH + kb);
      #pragma unroll
      for (int m=0;m<2;m++){
        acc[m][n] = __builtin_amdgcn_mfma_f32_16x16x32_f16(ah[m], bh, acc[m][n], 0,0,0);
        acc[m][n] = __builtin_amdgcn_mfma_f32_16x16x32_f16(al[m], bh, acc[m][n], 0,0,0);
        acc[m][n] = __builtin_amdgcn_mfma_f32_16x16x32_f16(ah[m], bl, acc[m][n], 0,0,0);
      }
    }
  }
  #pragma unroll
  for (int n=0;n<2;n++){
    const int j = n0 + n*16 + lm;
    const float bv = bias[j];
    #pragma unroll
    for (int m=0;m<2;m++){
      #pragma unroll
      for (int i=0;i<4;i++){
        int r = r0 + m*16 + q*4 + i;
        float cv = acc[m][n][i]*(1.0f/16.0f) + bv;
        if (SCALE) cv *= rowscale[r];
        C[(size_t)r*HH + j] = cv;
      }
    }
  }
}

// ---- edge gather: Eb[e,:] = invDE[e] * sum_{n in edge e} Xs[n,:] ----
__global__ __launch_bounds__(128)
void edge_gather(const float* __restrict__ Xs, const int* __restrict__ idx,
                 const int* __restrict__ cnt, const float* __restrict__ invDE,
                 float* __restrict__ Eb){
  __shared__ int sidx[MAXNNZ];
  const int e = blockIdx.x, h = threadIdx.x;
  const int c = cnt[e];
  for (int k = h; k < c; k += 128) sidx[k] = idx[e*MAXNNZ + k];
  __syncthreads();
  float acc = 0.0f;
  int k = 0;
  for (; k + 4 <= c; k += 4){
    float a0 = Xs[(size_t)sidx[k+0]*HH + h];
    float a1 = Xs[(size_t)sidx[k+1]*HH + h];
    float a2 = Xs[(size_t)sidx[k+2]*HH + h];
    float a3 = Xs[(size_t)sidx[k+3]*HH + h];
    acc += (a0 + a1) + (a2 + a3);
  }
  for (; k < c; ++k) acc += Xs[(size_t)sidx[k]*HH + h];
  Eb[e*HH + h] = invDE[e] * acc;
}

// ---- node gather: X[n,:] = epilogue( DV2[n] * sum_{e ∋ n} Eb[e,:] ) ----
template<int MODE>   // 1: relu(v)+poi   2: v
__global__ __launch_bounds__(128)
void node_gather(const float* __restrict__ Eb, const int* __restrict__ nidx,
                 const int* __restrict__ ndeg, const float* __restrict__ DV2,
                 const float* __restrict__ poi, float* __restrict__ Xo){
  __shared__ int sidx[MAXDEG];
  const int n = blockIdx.x, h = threadIdx.x;
  int c = ndeg[n]; c = c < MAXDEG ? c : MAXDEG;
  for (int k = h; k < c; k += 128) sidx[k] = nidx[n*MAXDEG + k];
  __syncthreads();
  float acc = 0.0f;
  int k = 0;
  for (; k + 4 <= c; k += 4){
    float a0 = Eb[(size_t)sidx[k+0]*HH + h];
    float a1 = Eb[(size_t)sidx[k+1]*HH + h];
    float a2 = Eb[(size_t)sidx[k+2]*HH + h];
    float a3 = Eb[(size_t)sidx[k+3]*HH + h];
    acc += (a0 + a1) + (a2 + a3);
  }
  for (; k < c; ++k) acc += Eb[(size_t)sidx[k]*HH + h];
  float v = DV2[n] * acc;
  if (MODE == 1) Xo[(size_t)n*HH + h] = fmaxf(v, 0.0f) + poi[(size_t)n*HH + h];
  else           Xo[(size_t)n*HH + h] = v;
}

__global__ __launch_bounds__(256)
void gather_emb(const float* __restrict__ X, const int* __restrict__ data, float* __restrict__ emb){
  int r = blockIdx.x*2 + (threadIdx.x >> 7);
  int h = threadIdx.x & 127;
  int n = data[r];
  emb[(size_t)r*HH + h] = X[(size_t)n*HH + h];
}

// ---- gx = (emb [+ relu(h)]) @ Wih^T + bih, MFMA fp16 hi/lo 3-product ----
template<bool FUSE>
__global__ __launch_bounds__(256)
void gx_gemm(const float* __restrict__ emb, const _Float16* __restrict__ hin,
             const _Float16* __restrict__ Whi, const _Float16* __restrict__ Wlo,
             const float* __restrict__ bih, const int* __restrict__ lens,
             float* __restrict__ gx)
{
  const int blk = blockIdx.x;
  const int b = blk >> 2, tt = blk & 3;
  const int lenb = lens[b];
  if (tt*32 >= lenb) return;
  const int tid = threadIdx.x;
  const int w = tid >> 6, l = tid & 63;
  const int lm = l & 15, q = l >> 4;
  const int r0 = b*TT + tt*32;
  const int n0 = w*96;

  f32x4 acc[2][6];
  #pragma unroll
  for (int m=0;m<2;m++)
    #pragma unroll
    for (int n=0;n<6;n++) acc[m][n] = (f32x4){0.f,0.f,0.f,0.f};

  #pragma unroll 1
  for (int ks = 0; ks < 4; ++ks){
    const int kb = ks*32 + q*8;
    f16x8 ah[2], al[2];
    #pragma unroll
    for (int m=0;m<2;m++){
      const size_t ro = (size_t)(r0 + m*16 + lm)*HH + kb;
      float4 f0 = *(const float4*)(emb + ro);
      float4 f1 = *(const float4*)(emb + ro + 4);
      float fv[8] = {f0.x,f0.y,f0.z,f0.w,f1.x,f1.y,f1.z,f1.w};
      if (FUSE){
        f16x8 hv = *(const f16x8*)(hin + ro);
        #pragma unroll
        for (int j=0;j<8;j++) fv[j] += fmaxf((float)hv[j], 0.0f);
      }
      union { f16x8 v; _Float16 u[8]; } uh, ul;
      #pragma unroll
      for (int j=0;j<8;j++){
        _Float16 hh = (_Float16)fv[j];
        uh.u[j] = hh;
        ul.u[j] = (_Float16)(fv[j] - (float)hh);
      }
      ah[m] = uh.v; al[m] = ul.v;
    }
    #pragma unroll
    for (int n=0;n<6;n++){
      const int g = n0 + n*16 + lm;
      f16x8 bh = *(const f16x8*)(Whi + (size_t)g*HH + kb);
      f16x8 bl = *(const f16x8*)(Wlo + (size_t)g*HH + kb);
      #pragma unroll
      for (int m=0;m<2;m++){
        acc[m][n] = __builtin_amdgcn_mfma_f32_16x16x32_f16(ah[m], bh, acc[m][n], 0,0,0);
        acc[m][n] = __builtin_amdgcn_mfma_f32_16x16x32_f16(al[m], bh, acc[m][n], 0,0,0);
        acc[m][n] = __builtin_amdgcn_mfma_f32_16x16x32_f16(ah[m], bl, acc[m][n], 0,0,0);
      }
    }
  }
  #pragma unroll
  for (int n=0;n<6;n++){
    const int g = n0 + n*16 + lm;
    const float bv = bih[g];
    #pragma unroll
    for (int m=0;m<2;m++){
      #pragma unroll
      for (int i=0;i<4;i++){
        int t = tt*32 + m*16 + q*4 + i;
        if (t < lenb)
          gx[((size_t)b*TT + t)*G3 + g] = acc[m][n][i]*(1.0f/16.0f) + bv;
      }
    }
  }
}

// ---- GRU scan v3: 2 batches/block, 256 blocks, 8 waves.
// Phase A: gh = h @ (16*Whh)^T via MFMA (batch rows 0-1 of 16-row tiles;
//          wave w owns output cols [w*48, w*48+48)), results to ghT LDS.
// Phase B: 256 threads, one (batch,dim) gate-triple each.
template<bool FINAL>
__global__ __launch_bounds__(512, 1)
void gru_scan3(const float* __restrict__ gxp, const float* __restrict__ Whh,
               const float* __restrict__ bhh, const int* __restrict__ lens,
               _Float16* __restrict__ hout, float* __restrict__ final_out)
{
  __shared__ _Float16 hbuf[2][16*HH];   // 8 KB; rows 2..15 stay zero
  __shared__ float ghT[2][392];         // [batch][col(384)+pad]
  const int tid = threadIdx.x;
  const int w = tid >> 6, lane = tid & 63;
  const int lm = lane & 15, q = lane >> 4;
  const int b0 = blockIdx.x * 2;

  // B-operand fragments: wave w covers cols w*48 + n*16 + lm (n=0..2), rows = Whh[col][:]
  f16x8 wf[3][4];
  #pragma unroll
  for (int n=0; n<3; ++n){
    const int col = w*48 + n*16 + lm;
    const float* wr = Whh + (size_t)col*HH;
    #pragma unroll
    for (int ks=0; ks<4; ++ks){
      const int kb = ks*32 + q*8;
      float4 f0 = *(const float4*)(wr + kb);
      float4 f1 = *(const float4*)(wr + kb + 4);
      float fv[8] = {f0.x,f0.y,f0.z,f0.w,f1.x,f1.y,f1.z,f1.w};
      union { f16x8 v; _Float16 u[8]; } uu;
      #pragma unroll
      for (int j=0;j<8;j++) uu.u[j] = (_Float16)(fv[j] * 16.0f);
      wf[n][ks] = uu.v;
    }
  }
  const float S = 1.0f/16.0f;
  const int lenmax = lens[b0];       // sorted descending

  // gate-phase mapping (tid < 256): batch gb, dim gd
  const int gb = tid >> 7, gd = tid & 127;
  float bR=0.f, bZ=0.f, bN=0.f; int glen=0;
  const float* gxrow = nullptr; _Float16* hrow = nullptr;
  if (tid < 256){
    bR = bhh[gd]; bZ = bhh[HH+gd]; bN = bhh[2*HH+gd];
    glen = lens[b0+gb];
    gxrow = gxp + (size_t)(b0+gb)*TT*G3;
    if (!FINAL) hrow = hout + (size_t)(b0+gb)*TT*HH + gd;
  }

  {   // zero both h buffers (rows 2..15 remain zero forever)
    unsigned int* z = (unsigned int*)&hbuf[0][0];
    #pragma unroll 1
    for (int i = tid; i < 2*16*HH/2; i += 512) z[i] = 0u;
  }
  __syncthreads();

  // prefetch t = 0
  float xv0=0.f, xv1=0.f, xv2=0.f, hp=0.f;
  if (tid < 256){ xv0 = gxrow[gd]; xv1 = gxrow[128+gd]; xv2 = gxrow[256+gd]; }

  int cur = 0;
  #pragma unroll 1
  for (int t = 0; t < lenmax; ++t){
    // ---- phase A: MFMA on all 8 waves ----
    f16x8 av[4];
    #pragma unroll
    for (int ks=0; ks<4; ++ks){
      int off = (lm*256 + ks*64 + q*16) ^ ((lm & 7) << 4);
      av[ks] = *(const f16x8*)((const char*)&hbuf[cur][0] + off);
    }
    // prefetch t+1 gx into regs (in flight across barriers; compiler waits at use)
    float xn0=0.f, xn1=0.f, xn2=0.f;
    if (tid < 256){
      int tp = (t+1 < lenmax) ? t+1 : t;
      const float* bgx = gxrow + (size_t)tp*G3;
      xn0 = bgx[gd]; xn1 = bgx[128+gd]; xn2 = bgx[256+gd];
    }
    f32x4 a0 = (f32x4){0.f,0.f,0.f,0.f}, a1 = a0, a2 = a0;
    #pragma unroll
    for (int ks=0; ks<4; ++ks){
      a0 = __builtin_amdgcn_mfma_f32_16x16x32_f16(av[ks], wf[0][ks], a0, 0,0,0);
      a1 = __builtin_amdgcn_mfma_f32_16x16x32_f16(av[ks], wf[1][ks], a1, 0,0,0);
      a2 = __builtin_amdgcn_mfma_f32_16x16x32_f16(av[ks], wf[2][ks], a2, 0,0,0);
    }
    if (q == 0){   // rows 0,1 = batches 0,1 live in acc[0], acc[1]
      const int c0 = w*48 + lm;
      ghT[0][c0]      = a0[0];  ghT[1][c0]      = a0[1];
      ghT[0][c0+16]   = a1[0];  ghT[1][c0+16]   = a1[1];
      ghT[0][c0+32]   = a2[0];  ghT[1][c0+32]   = a2[1];
    }
    bar_lds();

    // ---- phase B: one gate-triple per thread (tid < 256) ----
    if (tid < 256){
      float gr = ghT[gb][gd], gz = ghT[gb][128+gd], gn = ghT[gb][256+gd];
      float r = sigm(xv0 + gr*S + bR);
      float z = sigm(xv1 + gz*S + bZ);
      float n = tanhfast(xv2 + r*(gn*S + bN));
      float hnew = (1.0f - z)*n + z*hp;
      hp = hnew;
      int off = (gb*256 + gd*2) ^ (gb << 4);
      *(_Float16*)((char*)&hbuf[cur^1][0] + off) = (_Float16)hnew;
      if (!FINAL){
        hrow[(size_t)t*HH] = (_Float16)hnew;   // unconditional; masked downstream
      } else {
        if (t == glen - 1)
          final_out[(size_t)(b0+gb)*HH + gd] = tanhfast(hnew);
      }
    }
    xv0 = xn0; xv1 = xn1; xv2 = xn2;
    bar_lds();
    cur ^= 1;
  }
}

extern "C" void kernel_launch(void* const* d_in, const int* in_sizes, int n_in,
                              void* d_out, int out_size, void* d_ws, size_t ws_size,
                              hipStream_t stream)
{
  const float* Hb    = (const float*)d_in[0];
  const float* DV2   = (const float*)d_in[1];
  const float* invDE = (const float*)d_in[2];
  const int*   data  = (const int*)d_in[3];
  const int*   dlen  = (const int*)d_in[4];
  const float* poi   = (const float*)d_in[5];
  const float* w1    = (const float*)d_in[6];
  const float* b1    = (const float*)d_in[7];
  const float* w2    = (const float*)d_in[8];
  const float* b2    = (const float*)d_in[9];
  const float* Wih   = (const float*)d_in[10];
  const float* Whh   = (const float*)d_in[11];
  const float* bih   = (const float*)d_in[12];
  const float* bhh   = (const float*)d_in[13];
  float* out = (float*)d_out;

  float* ws   = (float*)d_ws;
  float* x1s  = ws;                          // N*H
  float* x2   = x1s + (size_t)NN*HH;         // N*H
  float* x3s  = x2  + (size_t)NN*HH;         // N*H
  float* x4   = x3s + (size_t)NN*HH;         // N*H
  float* ebuf = x4  + (size_t)NN*HH;         // E*H
  int*   idx  = (int*)(ebuf + (size_t)EE*HH);// E*MAXNNZ
  int*   cnt  = idx + (size_t)EE*MAXNNZ;     // E
  float* gx   = (float*)(cnt + EE);          // B*T*3H
  float* emb  = gx  + (size_t)BB*TT*G3;      // B*T*H
  _Float16* hout = (_Float16*)(emb + (size_t)BB*TT*HH); // B*T*H fp16
  _Float16* Whi  = hout + (size_t)BB*TT*HH;  // 3*384*128
  _Float16* Wlo  = Whi + (size_t)3*G3*HH;
  _Float16* w1th = Wlo + (size_t)3*G3*HH;    // 128*128 each
  _Float16* w1tl = w1th + (size_t)HH*HH;
  _Float16* w2th = w1tl + (size_t)HH*HH;
  _Float16* w2tl = w2th + (size_t)HH*HH;
  int* ndeg = (int*)(w2tl + (size_t)HH*HH);  // N
  int* nidx = ndeg + NN;                     // N*MAXDEG

  // ---- prep ----
  hipMemsetAsync(ndeg, 0, NN*sizeof(int), stream);
  build_nnz<<<EE, 256, 0, stream>>>(Hb, idx, cnt);
  build_nodelists<<<EE, 128, 0, stream>>>(idx, cnt, ndeg, nidx);
  prep_w<<<(3*G3*HH + 255)/256, 256, 0, stream>>>(Wih, Whi, Wlo, 3*G3*HH);
  prep_wt<<<HH*HH/256, 256, 0, stream>>>(w1, w1th, w1tl);
  prep_wt<<<HH*HH/256, 256, 0, stream>>>(w2, w2th, w2tl);

  // ---- hypergraph conv phase ----
  mm128_mfma<true><<<NN/32, 256, 0, stream>>>(poi, w1th, w1tl, b1, DV2, x1s);
  edge_gather<<<EE, 128, 0, stream>>>(x1s, idx, cnt, invDE, ebuf);
  node_gather<1><<<NN, 128, 0, stream>>>(ebuf, nidx, ndeg, DV2, poi, x2);
  mm128_mfma<true><<<NN/32, 256, 0, stream>>>(x2, w2th, w2tl, b2, DV2, x3s);
  edge_gather<<<EE, 128, 0, stream>>>(x3s, idx, cnt, invDE, ebuf);
  node_gather<2><<<NN, 128, 0, stream>>>(ebuf, nidx, ndeg, DV2, (const float*)nullptr, x4);
  gather_emb<<<BB*TT/2, 256, 0, stream>>>(x4, data, emb);

  // ---- GRU stack ----
  for (int l = 0; l < 3; ++l){
    if (l == 0)
      gx_gemm<false><<<BB*4, 256, 0, stream>>>(emb, (const _Float16*)nullptr,
          Whi + (size_t)l*G3*HH, Wlo + (size_t)l*G3*HH, bih + (size_t)l*G3, dlen, gx);
    else
      gx_gemm<true><<<BB*4, 256, 0, stream>>>(emb, hout,
          Whi + (size_t)l*G3*HH, Wlo + (size_t)l*G3*HH, bih + (size_t)l*G3, dlen, gx);
    if (l < 2)
      gru_scan3<false><<<BB/2, 512, 0, stream>>>(gx, Whh + (size_t)l*G3*HH,
          bhh + (size_t)l*G3, dlen, hout, (float*)nullptr);
    else
      gru_scan3<true><<<BB/2, 512, 0, stream>>>(gx, Whh + (size_t)l*G3*HH,
          bhh + (size_t)l*G3, dlen, (_Float16*)nullptr, out);
  }
}

// Round 8
// 580.354 us; speedup vs baseline: 1.4951x; 1.0019x over previous
//
#include <hip/hip_runtime.h>

#define NN 8192
#define EE 2048
#define BB 512
#define TT 128
#define HH 128
#define G3 384
#define MAXNNZ 256
#define MAXDEG 96

typedef __attribute__((ext_vector_type(8))) _Float16 f16x8;
typedef __attribute__((ext_vector_type(4))) float f32x4;

__device__ __forceinline__ float sigm(float x){ return 1.0f/(1.0f+__expf(-x)); }
__device__ __forceinline__ float tanhfast(float x){ return 2.0f/(1.0f+__expf(-2.0f*x)) - 1.0f; }

// barrier ordering LDS only; global loads/stores stay in flight.
__device__ __forceinline__ void bar_lds(){
  __builtin_amdgcn_sched_barrier(0);
  asm volatile("s_waitcnt lgkmcnt(0)\n\ts_barrier" ::: "memory");
  __builtin_amdgcn_sched_barrier(0);
}

// ---- build per-edge nonzero index lists (Hbat is exactly binary) ----
__global__ __launch_bounds__(256)
void build_nnz(const float* __restrict__ Hb, int* __restrict__ idx, int* __restrict__ cnt){
  __shared__ int c;
  const int e = blockIdx.x;
  if (threadIdx.x == 0) c = 0;
  __syncthreads();
  const float* row = Hb + (size_t)e * NN;
  for (int n = threadIdx.x; n < NN; n += 256){
    if (row[n] != 0.0f){
      int p = atomicAdd(&c, 1);
      if (p < MAXNNZ) idx[e*MAXNNZ + p] = n;
    }
  }
  __syncthreads();
  if (threadIdx.x == 0) cnt[e] = (c < MAXNNZ ? c : MAXNNZ);
}

// ---- invert edge lists into per-node edge lists ----
__global__ __launch_bounds__(128)
void build_nodelists(const int* __restrict__ idx, const int* __restrict__ cnt,
                     int* __restrict__ ndeg, int* __restrict__ nidx){
  const int e = blockIdx.x;
  const int c = cnt[e];
  for (int k = threadIdx.x; k < c; k += 128){
    int n = idx[e*MAXNNZ + k];
    int p = atomicAdd(&ndeg[n], 1);
    if (p < MAXDEG) nidx[n*MAXDEG + p] = e;
  }
}

// ---- split (16*W) into fp16 hi/lo, row-major passthrough ----
__global__ __launch_bounds__(256)
void prep_w(const float* __restrict__ W, _Float16* __restrict__ whi,
            _Float16* __restrict__ wlo, int n){
  int i = blockIdx.x*256 + threadIdx.x;
  if (i >= n) return;
  float g = W[i] * 16.0f;
  _Float16 h = (_Float16)g;
  whi[i] = h;
  wlo[i] = (_Float16)(g - (float)h);
}

// ---- plain split X into fp16 hi/lo (no scale) ----
__global__ __launch_bounds__(256)
void prep_split(const float* __restrict__ X, _Float16* __restrict__ hi,
                _Float16* __restrict__ lo, int n){
  int i = blockIdx.x*256 + threadIdx.x;
  if (i >= n) return;
  float v = X[i];
  _Float16 h = (_Float16)v;
  hi[i] = h;
  lo[i] = (_Float16)(v - (float)h);
}

// ---- transpose + split (16*W) 128x128: wt[j,k] = 16*W[k,j] ----
__global__ __launch_bounds__(256)
void prep_wt(const float* __restrict__ W, _Float16* __restrict__ wt_hi,
             _Float16* __restrict__ wt_lo){
  int i = blockIdx.x*256 + threadIdx.x;   // 16384 total
  int k = i >> 7, j = i & 127;
  float g = W[i] * 16.0f;
  _Float16 h = (_Float16)g;
  wt_hi[j*HH + k] = h;
  wt_lo[j*HH + k] = (_Float16)(g - (float)h);
}

// ---- conv-phase MFMA GEMM on pre-split A: C[r,j] = rowscale[r]*(A@W + bias) ----
template<bool SCALE>
__global__ __launch_bounds__(256)
void mm128_mfma(const _Float16* __restrict__ Ahi, const _Float16* __restrict__ Alo,
                const _Float16* __restrict__ Bh, const _Float16* __restrict__ Bl,
                const float* __restrict__ bias, const float* __restrict__ rowscale,
                float* __restrict__ C)
{
  const int tid = threadIdx.x;
  const int w = tid >> 6, l = tid & 63;
  const int lm = l & 15, q = l >> 4;
  const int r0 = blockIdx.x * 32;
  const int n0 = w * 32;

  f32x4 acc[2][2];
  #pragma unroll
  for (int m=0;m<2;m++)
    #pragma unroll
    for (int n=0;n<2;n++) acc[m][n] = (f32x4){0.f,0.f,0.f,0.f};

  #pragma unroll 2
  for (int ks = 0; ks < 4; ++ks){
    const int kb = ks*32 + q*8;
    f16x8 ah[2], al[2];
    #pragma unroll
    for (int m=0;m<2;m++){
      const size_t ro = (size_t)(r0 + m*16 + lm)*HH + kb;
      ah[m] = *(const f16x8*)(Ahi + ro);
      al[m] = *(const f16x8*)(Alo + ro);
    }
    #pragma unroll
    for (int n=0;n<2;n++){
      const int j = n0 + n*16 + lm;
      f16x8 bh = *(const f16x8*)(Bh + (size_t)j*HH + kb);
      f16x8 bl = *(const f16x8*)(Bl + (size_t)j*HH + kb);
      #pragma unroll
      for (int m=0;m<2;m++){
        acc[m][n] = __builtin_amdgcn_mfma_f32_16x16x32_f16(ah[m], bh, acc[m][n], 0,0,0);
        acc[m][n] = __builtin_amdgcn_mfma_f32_16x16x32_f16(al[m], bh, acc[m][n], 0,0,0);
        acc[m][n] = __builtin_amdgcn_mfma_f32_16x16x32_f16(ah[m], bl, acc[m][n], 0,0,0);
      }
    }
  }
  #pragma unroll
  for (int n=0;n<2;n++){
    const int j = n0 + n*16 + lm;
    const float bv = bias[j];
    #pragma unroll
    for (int m=0;m<2;m++){
      #pragma unroll
      for (int i=0;i<4;i++){
        int r = r0 + m*16 + q*4 + i;
        float cv = acc[m][n][i]*(1.0f/16.0f) + bv;
        if (SCALE) cv *= rowscale[r];
        C[(size_t)r*HH + j] = cv;
      }
    }
  }
}

// ---- edge gather: Eb[e,:] = invDE[e] * sum_{n in edge e} Xs[n,:] ----
__global__ __launch_bounds__(128)
void edge_gather(const float* __restrict__ Xs, const int* __restrict__ idx,
                 const int* __restrict__ cnt, const float* __restrict__ invDE,
                 float* __restrict__ Eb){
  __shared__ int sidx[MAXNNZ];
  const int e = blockIdx.x, h = threadIdx.x;
  const int c = cnt[e];
  for (int k = h; k < c; k += 128) sidx[k] = idx[e*MAXNNZ + k];
  __syncthreads();
  float acc = 0.0f;
  int k = 0;
  for (; k + 4 <= c; k += 4){
    float a0 = Xs[(size_t)sidx[k+0]*HH + h];
    float a1 = Xs[(size_t)sidx[k+1]*HH + h];
    float a2 = Xs[(size_t)sidx[k+2]*HH + h];
    float a3 = Xs[(size_t)sidx[k+3]*HH + h];
    acc += (a0 + a1) + (a2 + a3);
  }
  for (; k < c; ++k) acc += Xs[(size_t)sidx[k]*HH + h];
  Eb[e*HH + h] = invDE[e] * acc;
}

// ---- node gather: v = DV2[n] * sum_{e ∋ n} Eb[e,:]; MODE1: split(relu(v)+poi), MODE2: fp32 v ----
template<int MODE>
__global__ __launch_bounds__(128)
void node_gather(const float* __restrict__ Eb, const int* __restrict__ nidx,
                 const int* __restrict__ ndeg, const float* __restrict__ DV2,
                 const float* __restrict__ poi, _Float16* __restrict__ ohi,
                 _Float16* __restrict__ olo, float* __restrict__ Xo){
  __shared__ int sidx[MAXDEG];
  const int n = blockIdx.x, h = threadIdx.x;
  int c = ndeg[n]; c = c < MAXDEG ? c : MAXDEG;
  for (int k = h; k < c; k += 128) sidx[k] = nidx[n*MAXDEG + k];
  __syncthreads();
  float acc = 0.0f;
  int k = 0;
  for (; k + 4 <= c; k += 4){
    float a0 = Eb[(size_t)sidx[k+0]*HH + h];
    float a1 = Eb[(size_t)sidx[k+1]*HH + h];
    float a2 = Eb[(size_t)sidx[k+2]*HH + h];
    float a3 = Eb[(size_t)sidx[k+3]*HH + h];
    acc += (a0 + a1) + (a2 + a3);
  }
  for (; k < c; ++k) acc += Eb[(size_t)sidx[k]*HH + h];
  float v = DV2[n] * acc;
  if (MODE == 1){
    float val = fmaxf(v, 0.0f) + poi[(size_t)n*HH + h];
    _Float16 hh = (_Float16)val;
    ohi[(size_t)n*HH + h] = hh;
    olo[(size_t)n*HH + h] = (_Float16)(val - (float)hh);
  } else {
    Xo[(size_t)n*HH + h] = v;
  }
}

// ---- gather emb rows + write fp16 hi/lo split (layer-0 GEMM A operand) ----
__global__ __launch_bounds__(256)
void gather_emb(const float* __restrict__ X, const int* __restrict__ data,
                float* __restrict__ emb, _Float16* __restrict__ aHi,
                _Float16* __restrict__ aLo){
  int r = blockIdx.x*2 + (threadIdx.x >> 7);
  int h = threadIdx.x & 127;
  int n = data[r];
  float v = X[(size_t)n*HH + h];
  size_t o = (size_t)r*HH + h;
  emb[o] = v;
  _Float16 hh = (_Float16)v;
  aHi[o] = hh;
  aLo[o] = (_Float16)(v - (float)hh);
}

// ---- gx = A @ Wih^T + bih on pre-split A, fp16 hi/lo 3-product ----
__global__ __launch_bounds__(256)
void gx_gemm(const _Float16* __restrict__ Ahi, const _Float16* __restrict__ Alo,
             const _Float16* __restrict__ Whi, const _Float16* __restrict__ Wlo,
             const float* __restrict__ bih, const int* __restrict__ lens,
             float* __restrict__ gx)
{
  const int blk = blockIdx.x;
  const int b = blk >> 2, tt = blk & 3;
  const int lenb = lens[b];
  if (tt*32 >= lenb) return;
  const int tid = threadIdx.x;
  const int w = tid >> 6, l = tid & 63;
  const int lm = l & 15, q = l >> 4;
  const int r0 = b*TT + tt*32;
  const int n0 = w*96;

  f32x4 acc[2][6];
  #pragma unroll
  for (int m=0;m<2;m++)
    #pragma unroll
    for (int n=0;n<6;n++) acc[m][n] = (f32x4){0.f,0.f,0.f,0.f};

  #pragma unroll 2
  for (int ks = 0; ks < 4; ++ks){
    const int kb = ks*32 + q*8;
    f16x8 ah[2], al[2];
    #pragma unroll
    for (int m=0;m<2;m++){
      const size_t ro = (size_t)(r0 + m*16 + lm)*HH + kb;
      ah[m] = *(const f16x8*)(Ahi + ro);
      al[m] = *(const f16x8*)(Alo + ro);
    }
    #pragma unroll
    for (int n=0;n<6;n++){
      const int g = n0 + n*16 + lm;
      f16x8 bh = *(const f16x8*)(Whi + (size_t)g*HH + kb);
      f16x8 bl = *(const f16x8*)(Wlo + (size_t)g*HH + kb);
      #pragma unroll
      for (int m=0;m<2;m++){
        acc[m][n] = __builtin_amdgcn_mfma_f32_16x16x32_f16(ah[m], bh, acc[m][n], 0,0,0);
        acc[m][n] = __builtin_amdgcn_mfma_f32_16x16x32_f16(al[m], bh, acc[m][n], 0,0,0);
        acc[m][n] = __builtin_amdgcn_mfma_f32_16x16x32_f16(ah[m], bl, acc[m][n], 0,0,0);
      }
    }
  }
  #pragma unroll
  for (int n=0;n<6;n++){
    const int g = n0 + n*16 + lm;
    const float bv = bih[g];
    #pragma unroll
    for (int m=0;m<2;m++){
      #pragma unroll
      for (int i=0;i<4;i++){
        int t = tt*32 + m*16 + q*4 + i;
        gx[((size_t)b*TT + t)*G3 + g] = acc[m][n][i]*(1.0f/16.0f) + bv;
      }
    }
  }
}

// ---- GRU scan v3: 2 batches/block, 256 blocks, 8 waves.
// Phase A: gh = h @ (16*Whh)^T via MFMA -> ghT LDS.
// Phase B: 256 threads, one (batch,dim) triple; non-final layers also emit
//          the NEXT layer's pre-split A = emb + relu(h) directly.
template<bool FINAL>
__global__ __launch_bounds__(512, 1)
void gru_scan3(const float* __restrict__ gxp, const float* __restrict__ Whh,
               const float* __restrict__ bhh, const int* __restrict__ lens,
               const float* __restrict__ emb, _Float16* __restrict__ aHi,
               _Float16* __restrict__ aLo, float* __restrict__ final_out)
{
  __shared__ _Float16 hbuf[2][16*HH];   // 8 KB; rows 2..15 stay zero
  __shared__ float ghT[2][392];         // [batch][col(384)+pad]
  const int tid = threadIdx.x;
  const int w = tid >> 6, lane = tid & 63;
  const int lm = lane & 15, q = lane >> 4;
  const int b0 = blockIdx.x * 2;

  // B-operand fragments: wave w covers cols w*48 + n*16 + lm (n=0..2)
  f16x8 wf[3][4];
  #pragma unroll
  for (int n=0; n<3; ++n){
    const int col = w*48 + n*16 + lm;
    const float* wr = Whh + (size_t)col*HH;
    #pragma unroll
    for (int ks=0; ks<4; ++ks){
      const int kb = ks*32 + q*8;
      float4 f0 = *(const float4*)(wr + kb);
      float4 f1 = *(const float4*)(wr + kb + 4);
      float fv[8] = {f0.x,f0.y,f0.z,f0.w,f1.x,f1.y,f1.z,f1.w};
      union { f16x8 v; _Float16 u[8]; } uu;
      #pragma unroll
      for (int j=0;j<8;j++) uu.u[j] = (_Float16)(fv[j] * 16.0f);
      wf[n][ks] = uu.v;
    }
  }
  const float S = 1.0f/16.0f;
  const int lenmax = lens[b0];       // sorted descending

  // gate-phase mapping (tid < 256): batch gb, dim gd
  const int gb = tid >> 7, gd = tid & 127;
  float bR=0.f, bZ=0.f, bN=0.f; int glen=0;
  const float* gxrow = nullptr;
  const float* erow = nullptr;
  _Float16 *ahrow = nullptr, *alrow = nullptr;
  if (tid < 256){
    bR = bhh[gd]; bZ = bhh[HH+gd]; bN = bhh[2*HH+gd];
    glen = lens[b0+gb];
    gxrow = gxp + (size_t)(b0+gb)*TT*G3;
    if (!FINAL){
      erow  = emb + (size_t)(b0+gb)*TT*HH + gd;
      ahrow = aHi + (size_t)(b0+gb)*TT*HH + gd;
      alrow = aLo + (size_t)(b0+gb)*TT*HH + gd;
    }
  }

  {   // zero both h buffers (rows 2..15 remain zero forever)
    unsigned int* z = (unsigned int*)&hbuf[0][0];
    #pragma unroll 1
    for (int i = tid; i < 2*16*HH/2; i += 512) z[i] = 0u;
  }
  __syncthreads();

  // prefetch t = 0
  float xv0=0.f, xv1=0.f, xv2=0.f, xe=0.f, hp=0.f;
  if (tid < 256){
    xv0 = gxrow[gd]; xv1 = gxrow[128+gd]; xv2 = gxrow[256+gd];
    if (!FINAL) xe = erow[0];
  }

  int cur = 0;
  #pragma unroll 1
  for (int t = 0; t < lenmax; ++t){
    // ---- phase A: MFMA on all 8 waves ----
    f16x8 av[4];
    #pragma unroll
    for (int ks=0; ks<4; ++ks){
      int off = (lm*256 + ks*64 + q*16) ^ ((lm & 7) << 4);
      av[ks] = *(const f16x8*)((const char*)&hbuf[cur][0] + off);
    }
    // prefetch t+1 gx (+emb) into regs
    float xn0=0.f, xn1=0.f, xn2=0.f, xen=0.f;
    if (tid < 256){
      int tp = (t+1 < lenmax) ? t+1 : t;
      const float* bgx = gxrow + (size_t)tp*G3;
      xn0 = bgx[gd]; xn1 = bgx[128+gd]; xn2 = bgx[256+gd];
      if (!FINAL) xen = erow[(size_t)tp*HH];
    }
    f32x4 a0 = (f32x4){0.f,0.f,0.f,0.f}, a1 = a0, a2 = a0;
    #pragma unroll
    for (int ks=0; ks<4; ++ks){
      a0 = __builtin_amdgcn_mfma_f32_16x16x32_f16(av[ks], wf[0][ks], a0, 0,0,0);
      a1 = __builtin_amdgcn_mfma_f32_16x16x32_f16(av[ks], wf[1][ks], a1, 0,0,0);
      a2 = __builtin_amdgcn_mfma_f32_16x16x32_f16(av[ks], wf[2][ks], a2, 0,0,0);
    }
    if (q == 0){   // rows 0,1 = batches 0,1 live in acc[0], acc[1]
      const int c0 = w*48 + lm;
      ghT[0][c0]      = a0[0];  ghT[1][c0]      = a0[1];
      ghT[0][c0+16]   = a1[0];  ghT[1][c0+16]   = a1[1];
      ghT[0][c0+32]   = a2[0];  ghT[1][c0+32]   = a2[1];
    }
    bar_lds();

    // ---- phase B: one gate-triple per thread (tid < 256) ----
    if (tid < 256){
      float gr = ghT[gb][gd], gz = ghT[gb][128+gd], gn = ghT[gb][256+gd];
      float r = sigm(xv0 + gr*S + bR);
      float z = sigm(xv1 + gz*S + bZ);
      float n = tanhfast(xv2 + r*(gn*S + bN));
      float hnew = (1.0f - z)*n + z*hp;
      hp = hnew;
      int off = (gb*256 + gd*2) ^ (gb << 4);
      *(_Float16*)((char*)&hbuf[cur^1][0] + off) = (_Float16)hnew;
      if (!FINAL){
        float a = xe + fmaxf(hnew, 0.0f);
        _Float16 ah = (_Float16)a;
        ahrow[(size_t)t*HH] = ah;
        alrow[(size_t)t*HH] = (_Float16)(a - (float)ah);
      } else {
        if (t == glen - 1)
          final_out[(size_t)(b0+gb)*HH + gd] = tanhfast(hnew);
      }
    }
    xv0 = xn0; xv1 = xn1; xv2 = xn2; xe = xen;
    bar_lds();
    cur ^= 1;
  }
}

extern "C" void kernel_launch(void* const* d_in, const int* in_sizes, int n_in,
                              void* d_out, int out_size, void* d_ws, size_t ws_size,
                              hipStream_t stream)
{
  const float* Hb    = (const float*)d_in[0];
  const float* DV2   = (const float*)d_in[1];
  const float* invDE = (const float*)d_in[2];
  const int*   data  = (const int*)d_in[3];
  const int*   dlen  = (const int*)d_in[4];
  const float* poi   = (const float*)d_in[5];
  const float* w1    = (const float*)d_in[6];
  const float* b1    = (const float*)d_in[7];
  const float* w2    = (const float*)d_in[8];
  const float* b2    = (const float*)d_in[9];
  const float* Wih   = (const float*)d_in[10];
  const float* Whh   = (const float*)d_in[11];
  const float* bih   = (const float*)d_in[12];
  const float* bhh   = (const float*)d_in[13];
  float* out = (float*)d_out;

  float* ws   = (float*)d_ws;
  float* x1s  = ws;                          // N*H f32
  float* x3s  = x1s + (size_t)NN*HH;         // N*H f32
  float* x4   = x3s + (size_t)NN*HH;         // N*H f32
  float* ebuf = x4  + (size_t)NN*HH;         // E*H f32
  float* gx   = ebuf + (size_t)EE*HH;        // B*T*3H f32
  float* emb  = gx  + (size_t)BB*TT*G3;      // B*T*H f32
  _Float16* aHi  = (_Float16*)(emb + (size_t)BB*TT*HH); // B*T*H
  _Float16* aLo  = aHi + (size_t)BB*TT*HH;
  _Float16* x2hi = aLo + (size_t)BB*TT*HH;   // N*H
  _Float16* x2lo = x2hi + (size_t)NN*HH;
  _Float16* pHi  = x2lo + (size_t)NN*HH;     // N*H
  _Float16* pLo  = pHi + (size_t)NN*HH;
  _Float16* Whi  = pLo + (size_t)NN*HH;      // 3*384*128
  _Float16* Wlo  = Whi + (size_t)3*G3*HH;
  _Float16* w1th = Wlo + (size_t)3*G3*HH;    // 128*128 each
  _Float16* w1tl = w1th + (size_t)HH*HH;
  _Float16* w2th = w1tl + (size_t)HH*HH;
  _Float16* w2tl = w2th + (size_t)HH*HH;
  int* idx  = (int*)(w2tl + (size_t)HH*HH);  // E*MAXNNZ
  int* cnt  = idx + (size_t)EE*MAXNNZ;       // E
  int* ndeg = cnt + EE;                      // N
  int* nidx = ndeg + NN;                     // N*MAXDEG

  // ---- prep ----
  hipMemsetAsync(ndeg, 0, NN*sizeof(int), stream);
  build_nnz<<<EE, 256, 0, stream>>>(Hb, idx, cnt);
  build_nodelists<<<EE, 128, 0, stream>>>(idx, cnt, ndeg, nidx);
  prep_w<<<(3*G3*HH + 255)/256, 256, 0, stream>>>(Wih, Whi, Wlo, 3*G3*HH);
  prep_wt<<<HH*HH/256, 256, 0, stream>>>(w1, w1th, w1tl);
  prep_wt<<<HH*HH/256, 256, 0, stream>>>(w2, w2th, w2tl);
  prep_split<<<NN*HH/256, 256, 0, stream>>>(poi, pHi, pLo, NN*HH);

  // ---- hypergraph conv phase ----
  mm128_mfma<true><<<NN/32, 256, 0, stream>>>(pHi, pLo, w1th, w1tl, b1, DV2, x1s);
  edge_gather<<<EE, 128, 0, stream>>>(x1s, idx, cnt, invDE, ebuf);
  node_gather<1><<<NN, 128, 0, stream>>>(ebuf, nidx, ndeg, DV2, poi, x2hi, x2lo, (float*)nullptr);
  mm128_mfma<true><<<NN/32, 256, 0, stream>>>(x2hi, x2lo, w2th, w2tl, b2, DV2, x3s);
  edge_gather<<<EE, 128, 0, stream>>>(x3s, idx, cnt, invDE, ebuf);
  node_gather<2><<<NN, 128, 0, stream>>>(ebuf, nidx, ndeg, DV2, (const float*)nullptr,
                                         (_Float16*)nullptr, (_Float16*)nullptr, x4);
  gather_emb<<<BB*TT/2, 256, 0, stream>>>(x4, data, emb, aHi, aLo);

  // ---- GRU stack ----
  for (int l = 0; l < 3; ++l){
    gx_gemm<<<BB*4, 256, 0, stream>>>(aHi, aLo, Whi + (size_t)l*G3*HH,
        Wlo + (size_t)l*G3*HH, bih + (size_t)l*G3, dlen, gx);
    if (l < 2)
      gru_scan3<false><<<BB/2, 512, 0, stream>>>(gx, Whh + (size_t)l*G3*HH,
          bhh + (size_t)l*G3, dlen, emb, aHi, aLo, (float*)nullptr);
    else
      gru_scan3<true><<<BB/2, 512, 0, stream>>>(gx, Whh + (size_t)l*G3*HH,
          bhh + (size_t)l*G3, dlen, (const float*)nullptr,
          (_Float16*)nullptr, (_Float16*)nullptr, out);
  }
}